// Round 11
// baseline (1801.763 us; speedup 1.0000x reference)
//
#include <hip/hip_runtime.h>
#include <cstdio>
#include <type_traits>

#define NQ 10000
#define NT 50000
#define NA 50000
#define E_GR 50000
#define E_LT 50000
#define E_SIM 80000
#define E_COMP 100000
#define E_GEN 50000
#define MAXE 100000
#define NEG_SLOPE 0.2f

typedef unsigned short bf16_t;
typedef unsigned int u32;
typedef __attribute__((ext_vector_type(8))) short short8v;
typedef __attribute__((ext_vector_type(4))) float f32x4;

__device__ __forceinline__ float bf2f(u32 bits) { return __uint_as_float(bits << 16); }
__device__ __forceinline__ u32 f2bf(float f) {
  u32 u = __float_as_uint(f);
  return (u + 0x7FFFu + ((u >> 16) & 1u)) >> 16;   // RTNE
}
__device__ __forceinline__ u32 pack2(float a, float b) { return f2bf(a) | (f2bf(b) << 16); }
__device__ __forceinline__ void unpack8(uint4 u, float* f) {
  f[0] = bf2f(u.x & 0xffffu); f[1] = bf2f(u.x >> 16);
  f[2] = bf2f(u.y & 0xffffu); f[3] = bf2f(u.y >> 16);
  f[4] = bf2f(u.z & 0xffffu); f[5] = bf2f(u.z >> 16);
  f[6] = bf2f(u.w & 0xffffu); f[7] = bf2f(u.w >> 16);
}

// async global->LDS, 16B per lane; LDS dest = wave-uniform base + lane*16.
__device__ __forceinline__ void gload16(const void* g, void* l) {
  __builtin_amdgcn_global_load_lds(
      (const __attribute__((address_space(1))) void*)g,
      (__attribute__((address_space(3))) void*)l, 16, 0, 0);
}

// ---------------------------------------------------------------------------
// MFMA bf16 GEMM. C[N,M] = A[N,K] @ Bt[M,K]^T (+bias | +=C).
// 128x256 tile, BK=32, 512 threads = 8 waves (2 row x 4 col), wave tile
// 64x64, acc[4][4] (64 regs) -> ~124 unified regs -> 4 waves/SIMD =
// 2 blocks/CU (TLP covers barrier stalls; m114 cross-block overlap).
// LDS 2 bufs x (A 128x32 + B 256x32) shorts = 48KB.
// Per K-step: stage(s+1) [3 loads/thr] ; vmcnt(3) [drain cur only, next
// stays in flight] ; barrier (publish) ; ds_read + 16 MFMA ; barrier.
// Both-sides octet XOR (rule #21): store oct = (c&3)^((row>>1)&3), read
// oct = fg^((fr>>1)&3) -> exact 2-way bank aliasing (free, m136).
// XCD-grouped band swizzle; optional ridx A-row indirection.
// M%256==0, K%32==0; N guarded.
// ---------------------------------------------------------------------------
template <typename CT>
__global__ __launch_bounds__(512, 4) void bgemm(
    const bf16_t* __restrict__ A, const bf16_t* __restrict__ Bt,
    const float* __restrict__ bias, CT* __restrict__ C,
    const int* __restrict__ ridx, int N, int K, int M, int accumulate)
{
  __shared__ short lds[2][12288];   // [buf][A: 0..4095 | B: 4096..12287]
  const int tid = threadIdx.x;
  const int ncol = gridDim.x, nband = gridDim.y;

  // XCD-grouping swizzle (wg->XCD = id%8). Bijective incl. tail bands.
  int lin = blockIdx.y * ncol + blockIdx.x;
  int band, col;
  const int full = (nband >> 3) * 8 * ncol;
  if (lin < full) {
    int g = lin >> 3, x = lin & 7;
    band = x + 8 * (g / ncol);
    col  = g % ncol;
  } else {
    int r = lin - full;
    band = (nband & ~7) + r / ncol;
    col  = r % ncol;
  }
  const int bm = band * 128, bn = col * 256;

  const int lane = tid & 63;
  const int w = tid >> 6;          // 8 waves
  const int wr = w >> 2, wc = w & 3;
  const int fr = lane & 15, fg = lane >> 4;

  // staging: A 512 chunks (1/thread), B 1024 chunks (2/thread).
  // chunk c: row=c>>2, oct=c&3; global k-octet pre-swizzled (rule #21).
  const int kg = (((tid & 3) ^ ((tid >> 3) & 3)) << 3);
  const int rr = tid >> 2;
  int ra = min(bm + rr, N - 1);
  const bf16_t* gA0 = A + (size_t)(ridx ? ridx[ra] : ra) * K + kg;
  const bf16_t* gB0 = Bt + (size_t)(bn + rr) * K + kg;
  const bf16_t* gB1 = Bt + (size_t)(bn + 128 + rr) * K + kg;
  const int wb = w << 9;   // wave-uniform LDS short offset (64 chunks * 8)

  f32x4 acc[4][4];
#pragma unroll
  for (int i = 0; i < 4; ++i)
#pragma unroll
    for (int j = 0; j < 4; ++j) acc[i][j] = (f32x4){0.f, 0.f, 0.f, 0.f};

  auto stage = [&](int buf, int k0) {
    short* base = &lds[buf][0];
    gload16(gA0 + k0, base + wb);                  // A chunk t
    gload16(gB0 + k0, base + 4096 + wb);           // B chunk t
    gload16(gB1 + k0, base + 8192 + wb);           // B chunk t+512
  };

  const int nsteps = K >> 5;
  stage(0, 0);
  const int co = (fg ^ ((fr >> 1) & 3)) << 3;   // read-side XOR octet
  for (int s = 0; s < nsteps; ++s) {
    const int cur = s & 1;
    if (s + 1 < nsteps) {
      stage(cur ^ 1, (s + 1) << 5);
      asm volatile("s_waitcnt vmcnt(3)" ::: "memory");  // drain cur only
    } else {
      asm volatile("s_waitcnt vmcnt(0)" ::: "memory");
    }
    __builtin_amdgcn_s_barrier();            // publish buf[cur]
    asm volatile("" ::: "memory");
    const short* LA = &lds[cur][0];
    const short* LB = &lds[cur][4096];
    short8v b[4];
#pragma unroll
    for (int j = 0; j < 4; ++j) {
      int R = wc * 64 + j * 16 + fr;
      b[j] = *(const short8v*)&LB[R * 32 + co];
    }
#pragma unroll
    for (int i = 0; i < 4; ++i) {
      int R = wr * 64 + i * 16 + fr;
      short8v a = *(const short8v*)&LA[R * 32 + co];
#pragma unroll
      for (int j = 0; j < 4; ++j)
        acc[i][j] = __builtin_amdgcn_mfma_f32_16x16x32_bf16(b[j], a,
                                                            acc[i][j], 0, 0, 0);
    }
    asm volatile("" ::: "memory");
    __builtin_amdgcn_s_barrier();            // reads done before buf reuse
  }

  // epilogue: D cols (fr) = A rows; D row quad (fg*4+q) = C cols.
  float4 bv[4];
#pragma unroll
  for (int j = 0; j < 4; ++j) {
    bv[j] = make_float4(0.f, 0.f, 0.f, 0.f);
    if (!accumulate && bias)
      bv[j] = *(const float4*)(bias + bn + wc * 64 + j * 16 + fg * 4);
  }
#pragma unroll
  for (int i = 0; i < 4; ++i) {
    const int n = bm + wr * 64 + i * 16 + fr;
    if (n >= N) continue;
#pragma unroll
    for (int j = 0; j < 4; ++j) {
      const int m0 = bn + wc * 64 + j * 16 + fg * 4;
      f32x4 v = acc[i][j];
      if constexpr (std::is_same<CT, float>::value) {
        float* p = C + (size_t)n * M + m0;
        if (accumulate) {
          float4 o = *(float4*)p;
          o.x += v[0]; o.y += v[1]; o.z += v[2]; o.w += v[3];
          *(float4*)p = o;
        } else {
          *(float4*)p = make_float4(v[0] + bv[j].x, v[1] + bv[j].y,
                                    v[2] + bv[j].z, v[3] + bv[j].w);
        }
      } else {
        uint2 o;
        o.x = pack2(v[0] + bv[j].x, v[1] + bv[j].y);
        o.y = pack2(v[2] + bv[j].z, v[3] + bv[j].w);
        *(uint2*)(C + (size_t)n * M + m0) = o;
      }
    }
  }
}

// fp32 W[K][M] -> bf16 Wt[M][K] (transpose), 32x32 LDS tiles, z-batched.
__global__ __launch_bounds__(256) void convert_wT(
    const float* __restrict__ W, bf16_t* __restrict__ Wt, int K, int M)
{
  __shared__ float sm[32][33];
  W  += (size_t)blockIdx.z * K * M;
  Wt += (size_t)blockIdx.z * K * M;
  int mb = blockIdx.x * 32, kb = blockIdx.y * 32;
  int tx = threadIdx.x & 31, ty = threadIdx.x >> 5;
#pragma unroll
  for (int i = 0; i < 4; ++i)
    sm[ty + i * 8][tx] = W[(size_t)(kb + ty + i * 8) * M + mb + tx];
  __syncthreads();
#pragma unroll
  for (int i = 0; i < 4; ++i)
    Wt[(size_t)(mb + ty + i * 8) * K + kb + tx] = (bf16_t)f2bf(sm[tx][ty + i * 8]);
}

// fp32 -> bf16 flat cast, 4 elems/thread
__global__ __launch_bounds__(256) void f2bf_vec(
    const float* __restrict__ in, bf16_t* __restrict__ out, long n4)
{
  long t = (long)blockIdx.x * 256 + threadIdx.x;
  if (t >= n4) return;
  float4 v = ((const float4*)in)[t];
  uint2 o;
  o.x = pack2(v.x, v.y);
  o.y = pack2(v.z, v.w);
  ((uint2*)out)[t] = o;
}

// bc = (b0 [+b1] [+b2]) * inv  (512 floats)
__global__ __launch_bounds__(256) void combine_bias(
    const float* __restrict__ b0, const float* __restrict__ b1,
    const float* __restrict__ b2, float inv, float* __restrict__ out)
{
  int j = blockIdx.x * 256 + threadIdx.x;
  if (j >= 512) return;
  float v = b0[j];
  if (b1) v += b1[j];
  if (b2) v += b2[j];
  out[j] = v * inv;
}

// ---------------------------------------------------------------------------
// CSR build: histogram w/ slot assignment, 3-kernel exclusive scan, scatter.
// ---------------------------------------------------------------------------
__global__ __launch_bounds__(256) void csr_hist(
    const int* __restrict__ dst, int* __restrict__ deg, int* __restrict__ pos, int E)
{
  int e = blockIdx.x * 256 + threadIdx.x;
  if (e >= E) return;
  pos[e] = atomicAdd(&deg[dst[e]], 1);
}

__global__ __launch_bounds__(256) void scan1(
    const int* __restrict__ in, int* __restrict__ out, int* __restrict__ bsum, int n)
{
  __shared__ int sm[256];
  int t = threadIdx.x;
  int base = blockIdx.x * 1024 + t * 4;
  int v[4], sum = 0;
#pragma unroll
  for (int k = 0; k < 4; ++k) { v[k] = (base + k < n) ? in[base + k] : 0; sum += v[k]; }
  sm[t] = sum;
  __syncthreads();
  for (int off = 1; off < 256; off <<= 1) {
    int x = (t >= off) ? sm[t - off] : 0;
    __syncthreads();
    sm[t] += x;
    __syncthreads();
  }
  int run = (t > 0) ? sm[t - 1] : 0;
  if (t == 255) bsum[blockIdx.x] = sm[255];
#pragma unroll
  for (int k = 0; k < 4; ++k) {
    if (base + k < n) out[base + k] = run;
    run += v[k];
  }
}

__global__ __launch_bounds__(64) void scan2(int* __restrict__ bsum, int nb)
{
  __shared__ int sm[64];
  int t = threadIdx.x;
  int v = (t < nb) ? bsum[t] : 0;
  sm[t] = v;
  __syncthreads();
  for (int off = 1; off < 64; off <<= 1) {
    int x = (t >= off) ? sm[t - off] : 0;
    __syncthreads();
    sm[t] += x;
    __syncthreads();
  }
  if (t < nb) bsum[t] = sm[t] - v;   // exclusive
}

__global__ __launch_bounds__(256) void scan3(
    int* __restrict__ out, const int* __restrict__ bsum, int n)
{
  int g = blockIdx.x * 256 + threadIdx.x;
  if (g < n) out[g] += bsum[g >> 10];
}

__global__ __launch_bounds__(256) void csr_scatter(
    const int* __restrict__ dst, const int* __restrict__ start,
    const int* __restrict__ pos, int* __restrict__ eidx, int E)
{
  int e = blockIdx.x * 256 + threadIdx.x;
  if (e >= E) return;
  eidx[start[dst[e]] + pos[e]] = e;
}

// ---------------------------------------------------------------------------
// Fused GATv2 message+softmax+aggregate, one wave per dst node, no atomics.
// If bc != nullptr: also applies HeteroConv-mean + bias + relu (final
// relation for this node type) and writes the NEW h in place of acc.
// ---------------------------------------------------------------------------
__global__ __launch_bounds__(256) void gat_fused(
    const bf16_t* __restrict__ xl, const bf16_t* __restrict__ xr,
    const int* __restrict__ srcArr, const int* __restrict__ start,
    const int* __restrict__ deg, const int* __restrict__ eidx,
    const float* __restrict__ att, bf16_t* __restrict__ acc,
    int Nd, int accumulate, const float* __restrict__ bc, float inv_div)
{
  int d = blockIdx.x * 4 + (threadIdx.x >> 6);
  if (d >= Nd) return;
  int lane = threadIdx.x & 63;

  float xrr[8];
  unpack8(*(const uint4*)(xr + (size_t)d * 512 + lane * 8), xrr);
  float at[8];
  *(float4*)(at)     = *(const float4*)(att + lane * 8);
  *(float4*)(at + 4) = *(const float4*)(att + lane * 8 + 4);

  float acc8[8] = {0.f, 0.f, 0.f, 0.f, 0.f, 0.f, 0.f, 0.f};
  float den = 0.f;
  int n = deg[d], s0 = start[d];
  for (int i = 0; i < n; ++i) {
    int e = eidx[s0 + i];
    int s = srcArr[e];
    float f[8];
    unpack8(*(const uint4*)(xl + (size_t)s * 512 + lane * 8), f);
    float p = 0.f;
#pragma unroll
    for (int k = 0; k < 8; ++k) {
      float x = f[k] + xrr[k];
      p = fmaf(at[k], x >= 0.f ? x : NEG_SLOPE * x, p);
    }
#pragma unroll
    for (int m = 8; m >= 1; m >>= 1) p += __shfl_xor(p, m);  // 16-lane group = head
    float ex = __expf(p);
    den += ex;
#pragma unroll
    for (int k = 0; k < 8; ++k) acc8[k] = fmaf(ex, f[k], acc8[k]);
  }
  float inv = 1.f / (den + 1e-16f);
#pragma unroll
  for (int k = 0; k < 8; ++k) acc8[k] *= inv;

  bf16_t* out = acc + (size_t)d * 512 + lane * 8;
  if (accumulate) {
    float old[8];
    unpack8(*(const uint4*)out, old);
#pragma unroll
    for (int k = 0; k < 8; ++k) acc8[k] += old[k];
  }
  if (bc) {   // finalize: mean + combined bias + relu
    float bcv[8];
    *(float4*)(bcv)     = *(const float4*)(bc + lane * 8);
    *(float4*)(bcv + 4) = *(const float4*)(bc + lane * 8 + 4);
#pragma unroll
    for (int k = 0; k < 8; ++k)
      acc8[k] = fmaxf(fmaf(acc8[k], inv_div, bcv[k]), 0.f);
  }
  uint4 s;
  s.x = pack2(acc8[0], acc8[1]); s.y = pack2(acc8[2], acc8[3]);
  s.z = pack2(acc8[4], acc8[5]); s.w = pack2(acc8[6], acc8[7]);
  *(uint4*)out = s;
}

// afh = relu(answer_features @ W1 + b1) -> bf16, K=6, M=64
__global__ __launch_bounds__(256) void af_hidden(
    const float* __restrict__ af, const float* __restrict__ W1,
    const float* __restrict__ b1, bf16_t* __restrict__ out, int n)
{
  int t = blockIdx.x * blockDim.x + threadIdx.x;
  if (t >= n * 64) return;
  int i = t >> 6, j = t & 63;
  const float* a = af + (size_t)i * 6;
  float s = b1[j];
#pragma unroll
  for (int k = 0; k < 6; ++k) s = fmaf(a[k], W1[k * 64 + j], s);
  out[t] = (bf16_t)f2bf(fmaxf(s, 0.f));
}

__global__ __launch_bounds__(256) void build_sim(
    const int* __restrict__ ei, int* __restrict__ ss, int* __restrict__ sd)
{
  int t = blockIdx.x * blockDim.x + threadIdx.x;
  if (t >= E_SIM + NQ) return;
  if (t < E_SIM) { ss[t] = ei[t]; sd[t] = ei[E_SIM + t]; }
  else           { ss[t] = t - E_SIM; sd[t] = t - E_SIM; }
}

__global__ __launch_bounds__(256) void head_final(
    const float* __restrict__ qpre, const float* __restrict__ rpre,
    const float* __restrict__ qg, const float* __restrict__ qb,
    const float* __restrict__ rg, const float* __restrict__ rb,
    const float* __restrict__ score_bias, float* __restrict__ out, int E)
{
  int e = blockIdx.x * 4 + (threadIdx.x >> 6);
  if (e >= E) return;
  int lane = threadIdx.x & 63;

  float4 q = *(const float4*)(qpre + (size_t)e * 256 + lane * 4);
  float s = q.x + q.y + q.z + q.w;
#pragma unroll
  for (int m = 32; m >= 1; m >>= 1) s += __shfl_xor(s, m);
  float mu = s * (1.f / 256.f);
  float dq0 = q.x - mu, dq1 = q.y - mu, dq2 = q.z - mu, dq3 = q.w - mu;
  float v = dq0 * dq0 + dq1 * dq1 + dq2 * dq2 + dq3 * dq3;
#pragma unroll
  for (int m = 32; m >= 1; m >>= 1) v += __shfl_xor(v, m);
  float rstd = rsqrtf(v * (1.f / 256.f) + 1e-5f);
  float4 g4 = *(const float4*)(qg + lane * 4);
  float4 b4 = *(const float4*)(qb + lane * 4);
  float qn0 = dq0 * rstd * g4.x + b4.x, qn1 = dq1 * rstd * g4.y + b4.y;
  float qn2 = dq2 * rstd * g4.z + b4.z, qn3 = dq3 * rstd * g4.w + b4.w;

  float4 r = *(const float4*)(rpre + (size_t)e * 256 + lane * 4);
  s = r.x + r.y + r.z + r.w;
#pragma unroll
  for (int m = 32; m >= 1; m >>= 1) s += __shfl_xor(s, m);
  mu = s * (1.f / 256.f);
  float dr0 = r.x - mu, dr1 = r.y - mu, dr2 = r.z - mu, dr3 = r.w - mu;
  v = dr0 * dr0 + dr1 * dr1 + dr2 * dr2 + dr3 * dr3;
#pragma unroll
  for (int m = 32; m >= 1; m >>= 1) v += __shfl_xor(v, m);
  rstd = rsqrtf(v * (1.f / 256.f) + 1e-5f);
  g4 = *(const float4*)(rg + lane * 4);
  b4 = *(const float4*)(rb + lane * 4);
  float rn0 = dr0 * rstd * g4.x + b4.x, rn1 = dr1 * rstd * g4.y + b4.y;
  float rn2 = dr2 * rstd * g4.z + b4.z, rn3 = dr3 * rstd * g4.w + b4.w;

  float d = qn0 * rn0 + qn1 * rn1 + qn2 * rn2 + qn3 * rn3;
#pragma unroll
  for (int m = 32; m >= 1; m >>= 1) d += __shfl_xor(d, m);
  if (lane == 0) out[e] = d * 0.0625f + score_bias[0];
}

// ---------------------------------------------------------------------------
extern "C" void kernel_launch(void* const* d_in, const int* in_sizes, int n_in,
                              void* d_out, int out_size, void* d_ws, size_t ws_size,
                              hipStream_t stream) {
  (void)in_sizes; (void)n_in; (void)out_size;
  const float* xq      = (const float*)d_in[0];
  const float* xt      = (const float*)d_in[1];
  const float* xa      = (const float*)d_in[2];
  const float* af      = (const float*)d_in[3];
  const float* qp_W    = (const float*)d_in[4];
  const float* qp_b    = (const float*)d_in[5];
  const float* tp_W    = (const float*)d_in[6];
  const float* tp_b    = (const float*)d_in[7];
  const float* ap_W    = (const float*)d_in[8];
  const float* ap_b    = (const float*)d_in[9];
  const float* afp_W1  = (const float*)d_in[10];
  const float* afp_b1  = (const float*)d_in[11];
  const float* afp_W2  = (const float*)d_in[12];
  const float* afp_b2  = (const float*)d_in[13];
  const float* conv_Wl = (const float*)d_in[14];
  const float* conv_bl = (const float*)d_in[15];
  const float* conv_Wr = (const float*)d_in[16];
  const float* conv_br = (const float*)d_in[17];
  const float* conv_att  = (const float*)d_in[18];
  const float* conv_bias = (const float*)d_in[19];
  const float* qh_W    = (const float*)d_in[20];
  const float* qh_b    = (const float*)d_in[21];
  const float* qh_g    = (const float*)d_in[22];
  const float* qh_beta = (const float*)d_in[23];
  const float* rh_W    = (const float*)d_in[24];
  const float* rh_b    = (const float*)d_in[25];
  const float* rh_g    = (const float*)d_in[26];
  const float* rh_beta = (const float*)d_in[27];
  const float* score_b = (const float*)d_in[28];
  const int* ei_gr   = (const int*)d_in[29];
  const int* ei_lt   = (const int*)d_in[30];
  const int* ei_sim  = (const int*)d_in[31];
  const int* ei_comp = (const int*)d_in[32];
  const int* ei_gen  = (const int*)d_in[33];

  char* base = (char*)d_ws;
  size_t off = 0;
  auto alloc = [&](size_t bytes) {
    void* p = base + off;
    off = (off + bytes + 255) & ~(size_t)255;
    return p;
  };
  bf16_t* hq   = (bf16_t*)alloc((size_t)NQ * 512 * 2);
  bf16_t* ht   = (bf16_t*)alloc((size_t)NT * 512 * 2);
  bf16_t* ha   = (bf16_t*)alloc((size_t)NA * 512 * 2);
  bf16_t* acct = (bf16_t*)alloc((size_t)NT * 512 * 2);   // ht ping-pong; qpre f32
  bf16_t* accq = (bf16_t*)alloc((size_t)NQ * 512 * 2);   // hq ping-pong; afh bf16
  bf16_t* xlb  = (bf16_t*)alloc((size_t)50000 * 512 * 2);// staging/af_emb
  bf16_t* xrb  = (bf16_t*)alloc((size_t)50000 * 512 * 2);// also rpre f32
  int* simsrc  = (int*)alloc((size_t)(E_SIM + NQ) * 4);
  int* simdst  = (int*)alloc((size_t)(E_SIM + NQ) * 4);

  // bf16-transposed weights
  bf16_t* wqp  = (bf16_t*)alloc((size_t)512 * 384 * 2);
  bf16_t* wtp  = (bf16_t*)alloc((size_t)512 * 384 * 2);
  bf16_t* wap  = (bf16_t*)alloc((size_t)512 * 384 * 2);
  bf16_t* wl   = (bf16_t*)alloc((size_t)12 * 512 * 512 * 2);
  bf16_t* wr   = (bf16_t*)alloc((size_t)12 * 512 * 512 * 2);
  bf16_t* wafp2 = (bf16_t*)alloc((size_t)512 * 64 * 2);
  bf16_t* wqh  = (bf16_t*)alloc((size_t)256 * 512 * 2);
  bf16_t* wrh0 = (bf16_t*)alloc((size_t)256 * 512 * 2);
  bf16_t* wrh1 = (bf16_t*)alloc((size_t)256 * 512 * 2);
  bf16_t* wrh2 = (bf16_t*)alloc((size_t)256 * 512 * 2);
  float* bc_t  = (float*)alloc(512 * 4);
  float* bc_q  = (float*)alloc(512 * 4);
  float* bc_a  = (float*)alloc(512 * 4);

  // CSR topology. Order: 0=gr 1=rgr 2=rlt 3=sim 4=comp 5=lt (lt LAST)
  struct Topo { const int* src; const int* dst; int Nd, E; };
  Topo topo[6] = {
    {ei_gr,        ei_gr + E_GR,     NT, E_GR},
    {ei_gr + E_GR, ei_gr,            NQ, E_GR},
    {ei_lt + E_LT, ei_lt,            NT, E_LT},
    {simsrc,       simdst,           NQ, E_SIM + NQ},
    {ei_comp,      ei_comp + E_COMP, NT, E_COMP},
    {ei_lt,        ei_lt + E_LT,     NA, E_LT},
  };
  int *deg[6], *startp[6], *eidx[6];
  for (int r = 0; r < 6; ++r) {
    deg[r]    = (int*)alloc((size_t)topo[r].Nd * 4);
    startp[r] = (int*)alloc((size_t)topo[r].Nd * 4);
    eidx[r]   = (int*)alloc((size_t)topo[r].E * 4);
  }
  int* posb = (int*)alloc((size_t)MAXE * 4);
  int* bsum = (int*)alloc(64 * 4);
  if (off > ws_size) {
    fprintf(stderr, "kernel_launch: ws too small, need %zu have %zu\n", off, ws_size);
    return;
  }

  // --- weight conversion (fp32 [K][M] -> bf16 [M][K]) ---
  convert_wT<<<dim3(512 / 32, 512 / 32, 12), 256, 0, stream>>>(conv_Wl, wl, 512, 512);
  convert_wT<<<dim3(512 / 32, 512 / 32, 12), 256, 0, stream>>>(conv_Wr, wr, 512, 512);
  convert_wT<<<dim3(512 / 32, 384 / 32, 1), 256, 0, stream>>>(qp_W, wqp, 384, 512);
  convert_wT<<<dim3(512 / 32, 384 / 32, 1), 256, 0, stream>>>(tp_W, wtp, 384, 512);
  convert_wT<<<dim3(512 / 32, 384 / 32, 1), 256, 0, stream>>>(ap_W, wap, 384, 512);
  convert_wT<<<dim3(512 / 32, 64 / 32, 1), 256, 0, stream>>>(afp_W2, wafp2, 64, 512);
  convert_wT<<<dim3(256 / 32, 512 / 32, 1), 256, 0, stream>>>(qh_W, wqh, 512, 256);
  convert_wT<<<dim3(256 / 32, 512 / 32, 1), 256, 0, stream>>>(rh_W, wrh0, 512, 256);
  convert_wT<<<dim3(256 / 32, 512 / 32, 1), 256, 0, stream>>>(rh_W + 512 * 256, wrh1, 512, 256);
  convert_wT<<<dim3(256 / 32, 512 / 32, 1), 256, 0, stream>>>(rh_W + 1024 * 256, wrh2, 512, 256);

  build_sim<<<(E_SIM + NQ + 255) / 256, 256, 0, stream>>>(ei_sim, simsrc, simdst);
  for (int r = 0; r < 6; ++r) {
    const Topo& T = topo[r];
    hipMemsetAsync(deg[r], 0, (size_t)T.Nd * 4, stream);
    csr_hist<<<(T.E + 255) / 256, 256, 0, stream>>>(T.dst, deg[r], posb, T.E);
    int nb = (T.Nd + 1023) / 1024;
    scan1<<<nb, 256, 0, stream>>>(deg[r], startp[r], bsum, T.Nd);
    scan2<<<1, 64, 0, stream>>>(bsum, nb);
    scan3<<<(T.Nd + 255) / 256, 256, 0, stream>>>(startp[r], bsum, T.Nd);
    csr_scatter<<<(T.E + 255) / 256, 256, 0, stream>>>(T.dst, startp[r], posb,
                                                       eidx[r], T.E);
  }

  auto gemm = [&](const bf16_t* A, const bf16_t* Bt, const float* bias, bf16_t* C,
                  int N_, int K_, int M_, const int* ridx = nullptr) {
    dim3 g(M_ / 256, (N_ + 127) / 128);
    bgemm<bf16_t><<<g, 512, 0, stream>>>(A, Bt, bias, C, ridx, N_, K_, M_, 0);
  };
  auto gemmf = [&](const bf16_t* A, const bf16_t* Bt, const float* bias, float* C,
                   int N_, int K_, int M_, int acc_, const int* ridx = nullptr) {
    dim3 g(M_ / 256, (N_ + 127) / 128);
    bgemm<float><<<g, 512, 0, stream>>>(A, Bt, bias, C, ridx, N_, K_, M_, acc_);
  };

  // Input projections: cast fp32 inputs to bf16 in xlb, then MFMA GEMM.
  f2bf_vec<<<((long)NQ * 96 + 255) / 256, 256, 0, stream>>>(xq, xlb, (long)NQ * 96);
  gemm(xlb, wqp, qp_b, hq, NQ, 384, 512);
  f2bf_vec<<<((long)NT * 96 + 255) / 256, 256, 0, stream>>>(xt, xlb, (long)NT * 96);
  gemm(xlb, wtp, tp_b, ht, NT, 384, 512);
  f2bf_vec<<<((long)NA * 96 + 255) / 256, 256, 0, stream>>>(xa, xlb, (long)NA * 96);
  gemm(xlb, wap, ap_b, ha, NA, 384, 512);

  // Layer loop with ping-pong h buffers; last relation per dst type carries
  // the fused mean+bias+relu (bc != null) and produces the new h in acc.
  bf16_t *hq_i = hq, *ht_i = ht, *hq_o = accq, *ht_o = acct;
  for (int l = 0; l < 2; ++l) {
    size_t b = (size_t)l * 6;
    combine_bias<<<2, 256, 0, stream>>>(conv_bias + (b + 0) * 512,
        conv_bias + (b + 3) * 512, conv_bias + (b + 5) * 512, 1.f / 3.f, bc_t);
    combine_bias<<<2, 256, 0, stream>>>(conv_bias + (b + 1) * 512,
        conv_bias + (b + 4) * 512, nullptr, 0.5f, bc_q);
    combine_bias<<<2, 256, 0, stream>>>(conv_bias + (b + 2) * 512,
        nullptr, nullptr, 1.f, bc_a);

    struct Rel { const bf16_t* xs; const bf16_t* xd; int Ns, po; bf16_t* acc;
                 int accum; const float* bc; float inv; };
    Rel rels[6] = {
      {hq_i, ht_i, NQ, 0, ht_o, 0, nullptr, 0.f},      // gr
      {ht_i, hq_i, NT, 1, hq_o, 0, nullptr, 0.f},      // rgr
      {ha,   ht_i, NA, 3, ht_o, 1, nullptr, 0.f},      // rlt
      {hq_i, hq_i, NQ, 4, hq_o, 1, bc_q, 0.5f},        // sim (final for q)
      {ht_i, ht_i, NT, 5, ht_o, 1, bc_t, 1.f / 3.f},   // comp (final for t)
      {ht_i, ha,   NT, 2, ha,   0, bc_a, 1.f},         // lt (final for a, in-place)
    };
    for (int r = 0; r < 6; ++r) {
      const Rel& R = rels[r];
      const Topo& T = topo[r];
      size_t po = (size_t)l * 6 + R.po;
      gemm(R.xs, wl + po * 512 * 512, conv_bl + po * 512, xlb, R.Ns, 512, 512);
      gemm(R.xd, wr + po * 512 * 512, conv_br + po * 512, xrb, T.Nd, 512, 512);
      int gb = (T.Nd + 3) / 4;
      gat_fused<<<gb, 256, 0, stream>>>(xlb, xrb, T.src, startp[r], deg[r],
                                        eidx[r], conv_att + po * 512, R.acc,
                                        T.Nd, R.accum, R.bc, R.inv);
    }
    bf16_t* t;
    t = hq_i; hq_i = hq_o; hq_o = t;
    t = ht_i; ht_i = ht_o; ht_o = t;
  }
  // after 2 swaps: hq_i==hq, ht_i==ht; scratch acct/accq free again.

  // Head: gathers fused into bgemm via ridx. qpre(f32)->acct region,
  // rpre(f32)->xrb region, af_emb->xlb, afh(bf16)->accq.
  float* qpre = (float*)acct;
  float* rpre = (float*)xrb;
  bf16_t* afh = accq;
  const int* gsrc = ei_gen;
  const int* gdst = ei_gen + E_GEN;

  gemmf(hq_i, wqh, qh_b, qpre, E_GEN, 512, 256, 0, gsrc);    // q_emb @ qh_W
  gemmf(ht_i, wrh0, rh_b, rpre, E_GEN, 512, 256, 0, gdst);   // t_emb @ rh_W[0]
  gemmf(ha,  wrh1, nullptr, rpre, E_GEN, 512, 256, 1, gdst); // + a_emb @ rh_W[1]
  af_hidden<<<(E_GEN * 64 + 255) / 256, 256, 0, stream>>>(af, afp_W1, afp_b1,
                                                          afh, E_GEN);
  gemm(afh, wafp2, afp_b2, xlb, E_GEN, 64, 512);             // af_emb
  gemmf(xlb, wrh2, nullptr, rpre, E_GEN, 512, 256, 1);       // + af_emb @ rh_W[2]
  head_final<<<(E_GEN + 3) / 4, 256, 0, stream>>>(
      qpre, rpre, qh_g, qh_beta, rh_g, rh_beta, score_b, (float*)d_out, E_GEN);
}

// Round 12
// 1602.233 us; speedup vs baseline: 1.1245x; 1.1245x over previous
//
#include <hip/hip_runtime.h>
#include <cstdio>
#include <type_traits>

#define NQ 10000
#define NT 50000
#define NA 50000
#define E_GR 50000
#define E_LT 50000
#define E_SIM 80000
#define E_COMP 100000
#define E_GEN 50000
#define MAXE 100000
#define NEG_SLOPE 0.2f

typedef unsigned short bf16_t;
typedef unsigned int u32;
typedef __attribute__((ext_vector_type(8))) short short8v;
typedef __attribute__((ext_vector_type(4))) float f32x4;

__device__ __forceinline__ float bf2f(u32 bits) { return __uint_as_float(bits << 16); }
__device__ __forceinline__ u32 f2bf(float f) {
  u32 u = __float_as_uint(f);
  return (u + 0x7FFFu + ((u >> 16) & 1u)) >> 16;   // RTNE
}
__device__ __forceinline__ u32 pack2(float a, float b) { return f2bf(a) | (f2bf(b) << 16); }
__device__ __forceinline__ void unpack8(uint4 u, float* f) {
  f[0] = bf2f(u.x & 0xffffu); f[1] = bf2f(u.x >> 16);
  f[2] = bf2f(u.y & 0xffffu); f[3] = bf2f(u.y >> 16);
  f[4] = bf2f(u.z & 0xffffu); f[5] = bf2f(u.z >> 16);
  f[6] = bf2f(u.w & 0xffffu); f[7] = bf2f(u.w >> 16);
}

// async global->LDS, 16B per lane; LDS dest = wave-uniform base + lane*16.
__device__ __forceinline__ void gload16(const void* g, void* l) {
  __builtin_amdgcn_global_load_lds(
      (const __attribute__((address_space(1))) void*)g,
      (__attribute__((address_space(3))) void*)l, 16, 0, 0);
}

// ---------------------------------------------------------------------------
// MFMA bf16 GEMM, z-paired. For z in {0,1}: C_z = A_z @ Bt_z^T (+bias|+=C).
// 128x256 tile, BK=32, 512 threads = 8 waves (2x4), wave tile 64x64,
// acc[4][4]. LDS: THREE 24KB buffers (72KB -> 2 blocks/CU), rotation
// s%3 with ONE barrier per K-step:
//   stage buf[(s+1)%3] ; vmcnt(3) [own buf[s] loads] ; barrier ;
//   ds_read buf[s] + 16 MFMA ; (no trailing barrier)
// Safety: a wave at step s+1 writes buf[(s+2)%3]; laggards at step s read
// buf[s%3] (distinct); nobody can reach buf[s%3]-writing (step s+2) without
// passing step s+1's barrier, which waits for all. Reads of a buffer always
// complete before the owner's next barrier (lgkmcnt before last MFMA use).
// Both-sides octet XOR (rule #21): store oct = (c&3)^((row>>1)&3), read
// oct = fg^((fr>>1)&3) -> exact 2-way bank aliasing (free, m136).
// XCD-grouped band swizzle per z; optional ridx A-row indirection.
// M%256==0, K%32==0; N guarded; early exit uniform (before any barrier).
// ---------------------------------------------------------------------------
template <typename CT>
__global__ __launch_bounds__(512, 4) void bgemm(
    const bf16_t* __restrict__ A0, const bf16_t* __restrict__ Bt0,
    const float* __restrict__ bias0, CT* __restrict__ C0,
    const int* __restrict__ ridx0, int N0,
    const bf16_t* __restrict__ A1, const bf16_t* __restrict__ Bt1,
    const float* __restrict__ bias1, CT* __restrict__ C1,
    const int* __restrict__ ridx1, int N1,
    int K, int M, int accumulate)
{
  __shared__ short lds[3][12288];   // [buf][A: 0..4095 | B: 4096..12287]
  const int z = blockIdx.z;
  const bf16_t* A   = z ? A1 : A0;
  const bf16_t* Bt  = z ? Bt1 : Bt0;
  const float* bias = z ? bias1 : bias0;
  CT* C             = z ? C1 : C0;
  const int* ridx   = z ? ridx1 : ridx0;
  const int N       = z ? N1 : N0;

  const int tid = threadIdx.x;
  const int ncol = gridDim.x;
  const int nband = (N + 127) >> 7;         // per-z band count
  int lin = blockIdx.y * ncol + blockIdx.x;
  if (lin >= ncol * nband) return;          // uniform exit, before barriers

  // XCD-grouping swizzle (wg->XCD = id%8). Bijective incl. tail bands.
  int band, col;
  const int full = (nband >> 3) * 8 * ncol;
  if (lin < full) {
    int g = lin >> 3, x = lin & 7;
    band = x + 8 * (g / ncol);
    col  = g % ncol;
  } else {
    int r = lin - full;
    band = (nband & ~7) + r / ncol;
    col  = r % ncol;
  }
  const int bm = band * 128, bn = col * 256;

  const int lane = tid & 63;
  const int w = tid >> 6;          // 8 waves
  const int wr = w >> 2, wc = w & 3;
  const int fr = lane & 15, fg = lane >> 4;

  // staging: A 512 chunks (1/thread), B 1024 chunks (2/thread).
  // chunk c: row=c>>2, oct=c&3; global k-octet pre-swizzled (rule #21).
  const int kg = (((tid & 3) ^ ((tid >> 3) & 3)) << 3);
  const int rr = tid >> 2;
  int ra = min(bm + rr, N - 1);
  const bf16_t* gA0 = A + (size_t)(ridx ? ridx[ra] : ra) * K + kg;
  const bf16_t* gB0 = Bt + (size_t)(bn + rr) * K + kg;
  const bf16_t* gB1 = Bt + (size_t)(bn + 128 + rr) * K + kg;
  const int wb = w << 9;   // wave-uniform LDS short offset (64 chunks * 8)

  f32x4 acc[4][4];
#pragma unroll
  for (int i = 0; i < 4; ++i)
#pragma unroll
    for (int j = 0; j < 4; ++j) acc[i][j] = (f32x4){0.f, 0.f, 0.f, 0.f};

  auto stage = [&](int buf, int k0) {
    short* base = &lds[buf][0];
    gload16(gA0 + k0, base + wb);                  // A chunk t
    gload16(gB0 + k0, base + 4096 + wb);           // B chunk t
    gload16(gB1 + k0, base + 8192 + wb);           // B chunk t+512
  };

  const int nsteps = K >> 5;
  stage(0, 0);
  const int co = (fg ^ ((fr >> 1) & 3)) << 3;   // read-side XOR octet
  for (int s = 0; s < nsteps; ++s) {
    const int cur = s % 3;
    if (s + 1 < nsteps) {
      stage((s + 1) % 3, (s + 1) << 5);
      asm volatile("s_waitcnt vmcnt(3)" ::: "memory");  // drain cur only
    } else {
      asm volatile("s_waitcnt vmcnt(0)" ::: "memory");
    }
    __builtin_amdgcn_s_barrier();            // publish buf[cur]
    asm volatile("" ::: "memory");
    const short* LA = &lds[cur][0];
    const short* LB = &lds[cur][4096];
    short8v b[4];
#pragma unroll
    for (int j = 0; j < 4; ++j) {
      int R = wc * 64 + j * 16 + fr;
      b[j] = *(const short8v*)&LB[R * 32 + co];
    }
#pragma unroll
    for (int i = 0; i < 4; ++i) {
      int R = wr * 64 + i * 16 + fr;
      short8v a = *(const short8v*)&LA[R * 32 + co];
#pragma unroll
      for (int j = 0; j < 4; ++j)
        acc[i][j] = __builtin_amdgcn_mfma_f32_16x16x32_bf16(b[j], a,
                                                            acc[i][j], 0, 0, 0);
    }
    asm volatile("" ::: "memory");
    // no trailing barrier: 3-buffer rotation makes it safe (see header)
  }

  // epilogue: D cols (fr) = A rows; D row quad (fg*4+q) = C cols.
  float4 bv[4];
#pragma unroll
  for (int j = 0; j < 4; ++j) {
    bv[j] = make_float4(0.f, 0.f, 0.f, 0.f);
    if (!accumulate && bias)
      bv[j] = *(const float4*)(bias + bn + wc * 64 + j * 16 + fg * 4);
  }
#pragma unroll
  for (int i = 0; i < 4; ++i) {
    const int n = bm + wr * 64 + i * 16 + fr;
    if (n >= N) continue;
#pragma unroll
    for (int j = 0; j < 4; ++j) {
      const int m0 = bn + wc * 64 + j * 16 + fg * 4;
      f32x4 v = acc[i][j];
      if constexpr (std::is_same<CT, float>::value) {
        float* p = C + (size_t)n * M + m0;
        if (accumulate) {
          float4 o = *(float4*)p;
          o.x += v[0]; o.y += v[1]; o.z += v[2]; o.w += v[3];
          *(float4*)p = o;
        } else {
          *(float4*)p = make_float4(v[0] + bv[j].x, v[1] + bv[j].y,
                                    v[2] + bv[j].z, v[3] + bv[j].w);
        }
      } else {
        uint2 o;
        o.x = pack2(v[0] + bv[j].x, v[1] + bv[j].y);
        o.y = pack2(v[2] + bv[j].z, v[3] + bv[j].w);
        *(uint2*)(C + (size_t)n * M + m0) = o;
      }
    }
  }
}

// fp32 W[K][M] -> bf16 Wt[M][K] (transpose), 32x32 LDS tiles, z-batched.
__global__ __launch_bounds__(256) void convert_wT(
    const float* __restrict__ W, bf16_t* __restrict__ Wt, int K, int M)
{
  __shared__ float sm[32][33];
  W  += (size_t)blockIdx.z * K * M;
  Wt += (size_t)blockIdx.z * K * M;
  int mb = blockIdx.x * 32, kb = blockIdx.y * 32;
  int tx = threadIdx.x & 31, ty = threadIdx.x >> 5;
#pragma unroll
  for (int i = 0; i < 4; ++i)
    sm[ty + i * 8][tx] = W[(size_t)(kb + ty + i * 8) * M + mb + tx];
  __syncthreads();
#pragma unroll
  for (int i = 0; i < 4; ++i)
    Wt[(size_t)(mb + ty + i * 8) * K + kb + tx] = (bf16_t)f2bf(sm[tx][ty + i * 8]);
}

// fp32 -> bf16 flat cast, 4 elems/thread
__global__ __launch_bounds__(256) void f2bf_vec(
    const float* __restrict__ in, bf16_t* __restrict__ out, long n4)
{
  long t = (long)blockIdx.x * 256 + threadIdx.x;
  if (t >= n4) return;
  float4 v = ((const float4*)in)[t];
  uint2 o;
  o.x = pack2(v.x, v.y);
  o.y = pack2(v.z, v.w);
  ((uint2*)out)[t] = o;
}

// bc = (b0 [+b1] [+b2]) * inv  (512 floats)
__global__ __launch_bounds__(256) void combine_bias(
    const float* __restrict__ b0, const float* __restrict__ b1,
    const float* __restrict__ b2, float inv, float* __restrict__ out)
{
  int j = blockIdx.x * 256 + threadIdx.x;
  if (j >= 512) return;
  float v = b0[j];
  if (b1) v += b1[j];
  if (b2) v += b2[j];
  out[j] = v * inv;
}

// ---------------------------------------------------------------------------
// CSR build: histogram w/ slot assignment, 3-kernel exclusive scan, scatter.
// ---------------------------------------------------------------------------
__global__ __launch_bounds__(256) void csr_hist(
    const int* __restrict__ dst, int* __restrict__ deg, int* __restrict__ pos, int E)
{
  int e = blockIdx.x * 256 + threadIdx.x;
  if (e >= E) return;
  pos[e] = atomicAdd(&deg[dst[e]], 1);
}

__global__ __launch_bounds__(256) void scan1(
    const int* __restrict__ in, int* __restrict__ out, int* __restrict__ bsum, int n)
{
  __shared__ int sm[256];
  int t = threadIdx.x;
  int base = blockIdx.x * 1024 + t * 4;
  int v[4], sum = 0;
#pragma unroll
  for (int k = 0; k < 4; ++k) { v[k] = (base + k < n) ? in[base + k] : 0; sum += v[k]; }
  sm[t] = sum;
  __syncthreads();
  for (int off = 1; off < 256; off <<= 1) {
    int x = (t >= off) ? sm[t - off] : 0;
    __syncthreads();
    sm[t] += x;
    __syncthreads();
  }
  int run = (t > 0) ? sm[t - 1] : 0;
  if (t == 255) bsum[blockIdx.x] = sm[255];
#pragma unroll
  for (int k = 0; k < 4; ++k) {
    if (base + k < n) out[base + k] = run;
    run += v[k];
  }
}

__global__ __launch_bounds__(64) void scan2(int* __restrict__ bsum, int nb)
{
  __shared__ int sm[64];
  int t = threadIdx.x;
  int v = (t < nb) ? bsum[t] : 0;
  sm[t] = v;
  __syncthreads();
  for (int off = 1; off < 64; off <<= 1) {
    int x = (t >= off) ? sm[t - off] : 0;
    __syncthreads();
    sm[t] += x;
    __syncthreads();
  }
  if (t < nb) bsum[t] = sm[t] - v;   // exclusive
}

__global__ __launch_bounds__(256) void scan3(
    int* __restrict__ out, const int* __restrict__ bsum, int n)
{
  int g = blockIdx.x * 256 + threadIdx.x;
  if (g < n) out[g] += bsum[g >> 10];
}

__global__ __launch_bounds__(256) void csr_scatter(
    const int* __restrict__ dst, const int* __restrict__ start,
    const int* __restrict__ pos, int* __restrict__ eidx, int E)
{
  int e = blockIdx.x * 256 + threadIdx.x;
  if (e >= E) return;
  eidx[start[dst[e]] + pos[e]] = e;
}

// ---------------------------------------------------------------------------
// Fused GATv2 message+softmax+aggregate, one wave per dst node, no atomics.
// If bc != nullptr: also applies HeteroConv-mean + bias + relu (final
// relation for this node type) and writes the NEW h in place of acc.
// ---------------------------------------------------------------------------
__global__ __launch_bounds__(256) void gat_fused(
    const bf16_t* __restrict__ xl, const bf16_t* __restrict__ xr,
    const int* __restrict__ srcArr, const int* __restrict__ start,
    const int* __restrict__ deg, const int* __restrict__ eidx,
    const float* __restrict__ att, bf16_t* __restrict__ acc,
    int Nd, int accumulate, const float* __restrict__ bc, float inv_div)
{
  int d = blockIdx.x * 4 + (threadIdx.x >> 6);
  if (d >= Nd) return;
  int lane = threadIdx.x & 63;

  float xrr[8];
  unpack8(*(const uint4*)(xr + (size_t)d * 512 + lane * 8), xrr);
  float at[8];
  *(float4*)(at)     = *(const float4*)(att + lane * 8);
  *(float4*)(at + 4) = *(const float4*)(att + lane * 8 + 4);

  float acc8[8] = {0.f, 0.f, 0.f, 0.f, 0.f, 0.f, 0.f, 0.f};
  float den = 0.f;
  int n = deg[d], s0 = start[d];
  for (int i = 0; i < n; ++i) {
    int e = eidx[s0 + i];
    int s = srcArr[e];
    float f[8];
    unpack8(*(const uint4*)(xl + (size_t)s * 512 + lane * 8), f);
    float p = 0.f;
#pragma unroll
    for (int k = 0; k < 8; ++k) {
      float x = f[k] + xrr[k];
      p = fmaf(at[k], x >= 0.f ? x : NEG_SLOPE * x, p);
    }
#pragma unroll
    for (int m = 8; m >= 1; m >>= 1) p += __shfl_xor(p, m);  // 16-lane group = head
    float ex = __expf(p);
    den += ex;
#pragma unroll
    for (int k = 0; k < 8; ++k) acc8[k] = fmaf(ex, f[k], acc8[k]);
  }
  float inv = 1.f / (den + 1e-16f);
#pragma unroll
  for (int k = 0; k < 8; ++k) acc8[k] *= inv;

  bf16_t* out = acc + (size_t)d * 512 + lane * 8;
  if (accumulate) {
    float old[8];
    unpack8(*(const uint4*)out, old);
#pragma unroll
    for (int k = 0; k < 8; ++k) acc8[k] += old[k];
  }
  if (bc) {   // finalize: mean + combined bias + relu
    float bcv[8];
    *(float4*)(bcv)     = *(const float4*)(bc + lane * 8);
    *(float4*)(bcv + 4) = *(const float4*)(bc + lane * 8 + 4);
#pragma unroll
    for (int k = 0; k < 8; ++k)
      acc8[k] = fmaxf(fmaf(acc8[k], inv_div, bcv[k]), 0.f);
  }
  uint4 s;
  s.x = pack2(acc8[0], acc8[1]); s.y = pack2(acc8[2], acc8[3]);
  s.z = pack2(acc8[4], acc8[5]); s.w = pack2(acc8[6], acc8[7]);
  *(uint4*)out = s;
}

// afh = relu(answer_features @ W1 + b1) -> bf16, K=6, M=64
__global__ __launch_bounds__(256) void af_hidden(
    const float* __restrict__ af, const float* __restrict__ W1,
    const float* __restrict__ b1, bf16_t* __restrict__ out, int n)
{
  int t = blockIdx.x * blockDim.x + threadIdx.x;
  if (t >= n * 64) return;
  int i = t >> 6, j = t & 63;
  const float* a = af + (size_t)i * 6;
  float s = b1[j];
#pragma unroll
  for (int k = 0; k < 6; ++k) s = fmaf(a[k], W1[k * 64 + j], s);
  out[t] = (bf16_t)f2bf(fmaxf(s, 0.f));
}

__global__ __launch_bounds__(256) void build_sim(
    const int* __restrict__ ei, int* __restrict__ ss, int* __restrict__ sd)
{
  int t = blockIdx.x * blockDim.x + threadIdx.x;
  if (t >= E_SIM + NQ) return;
  if (t < E_SIM) { ss[t] = ei[t]; sd[t] = ei[E_SIM + t]; }
  else           { ss[t] = t - E_SIM; sd[t] = t - E_SIM; }
}

__global__ __launch_bounds__(256) void head_final(
    const float* __restrict__ qpre, const float* __restrict__ rpre,
    const float* __restrict__ qg, const float* __restrict__ qb,
    const float* __restrict__ rg, const float* __restrict__ rb,
    const float* __restrict__ score_bias, float* __restrict__ out, int E)
{
  int e = blockIdx.x * 4 + (threadIdx.x >> 6);
  if (e >= E) return;
  int lane = threadIdx.x & 63;

  float4 q = *(const float4*)(qpre + (size_t)e * 256 + lane * 4);
  float s = q.x + q.y + q.z + q.w;
#pragma unroll
  for (int m = 32; m >= 1; m >>= 1) s += __shfl_xor(s, m);
  float mu = s * (1.f / 256.f);
  float dq0 = q.x - mu, dq1 = q.y - mu, dq2 = q.z - mu, dq3 = q.w - mu;
  float v = dq0 * dq0 + dq1 * dq1 + dq2 * dq2 + dq3 * dq3;
#pragma unroll
  for (int m = 32; m >= 1; m >>= 1) v += __shfl_xor(v, m);
  float rstd = rsqrtf(v * (1.f / 256.f) + 1e-5f);
  float4 g4 = *(const float4*)(qg + lane * 4);
  float4 b4 = *(const float4*)(qb + lane * 4);
  float qn0 = dq0 * rstd * g4.x + b4.x, qn1 = dq1 * rstd * g4.y + b4.y;
  float qn2 = dq2 * rstd * g4.z + b4.z, qn3 = dq3 * rstd * g4.w + b4.w;

  float4 r = *(const float4*)(rpre + (size_t)e * 256 + lane * 4);
  s = r.x + r.y + r.z + r.w;
#pragma unroll
  for (int m = 32; m >= 1; m >>= 1) s += __shfl_xor(s, m);
  mu = s * (1.f / 256.f);
  float dr0 = r.x - mu, dr1 = r.y - mu, dr2 = r.z - mu, dr3 = r.w - mu;
  v = dr0 * dr0 + dr1 * dr1 + dr2 * dr2 + dr3 * dr3;
#pragma unroll
  for (int m = 32; m >= 1; m >>= 1) v += __shfl_xor(v, m);
  rstd = rsqrtf(v * (1.f / 256.f) + 1e-5f);
  g4 = *(const float4*)(rg + lane * 4);
  b4 = *(const float4*)(rb + lane * 4);
  float rn0 = dr0 * rstd * g4.x + b4.x, rn1 = dr1 * rstd * g4.y + b4.y;
  float rn2 = dr2 * rstd * g4.z + b4.z, rn3 = dr3 * rstd * g4.w + b4.w;

  float d = qn0 * rn0 + qn1 * rn1 + qn2 * rn2 + qn3 * rn3;
#pragma unroll
  for (int m = 32; m >= 1; m >>= 1) d += __shfl_xor(d, m);
  if (lane == 0) out[e] = d * 0.0625f + score_bias[0];
}

// ---------------------------------------------------------------------------
extern "C" void kernel_launch(void* const* d_in, const int* in_sizes, int n_in,
                              void* d_out, int out_size, void* d_ws, size_t ws_size,
                              hipStream_t stream) {
  (void)in_sizes; (void)n_in; (void)out_size;
  const float* xq      = (const float*)d_in[0];
  const float* xt      = (const float*)d_in[1];
  const float* xa      = (const float*)d_in[2];
  const float* af      = (const float*)d_in[3];
  const float* qp_W    = (const float*)d_in[4];
  const float* qp_b    = (const float*)d_in[5];
  const float* tp_W    = (const float*)d_in[6];
  const float* tp_b    = (const float*)d_in[7];
  const float* ap_W    = (const float*)d_in[8];
  const float* ap_b    = (const float*)d_in[9];
  const float* afp_W1  = (const float*)d_in[10];
  const float* afp_b1  = (const float*)d_in[11];
  const float* afp_W2  = (const float*)d_in[12];
  const float* afp_b2  = (const float*)d_in[13];
  const float* conv_Wl = (const float*)d_in[14];
  const float* conv_bl = (const float*)d_in[15];
  const float* conv_Wr = (const float*)d_in[16];
  const float* conv_br = (const float*)d_in[17];
  const float* conv_att  = (const float*)d_in[18];
  const float* conv_bias = (const float*)d_in[19];
  const float* qh_W    = (const float*)d_in[20];
  const float* qh_b    = (const float*)d_in[21];
  const float* qh_g    = (const float*)d_in[22];
  const float* qh_beta = (const float*)d_in[23];
  const float* rh_W    = (const float*)d_in[24];
  const float* rh_b    = (const float*)d_in[25];
  const float* rh_g    = (const float*)d_in[26];
  const float* rh_beta = (const float*)d_in[27];
  const float* score_b = (const float*)d_in[28];
  const int* ei_gr   = (const int*)d_in[29];
  const int* ei_lt   = (const int*)d_in[30];
  const int* ei_sim  = (const int*)d_in[31];
  const int* ei_comp = (const int*)d_in[32];
  const int* ei_gen  = (const int*)d_in[33];

  char* base = (char*)d_ws;
  size_t off = 0;
  auto alloc = [&](size_t bytes) {
    void* p = base + off;
    off = (off + bytes + 255) & ~(size_t)255;
    return p;
  };
  bf16_t* hq   = (bf16_t*)alloc((size_t)NQ * 512 * 2);
  bf16_t* ht   = (bf16_t*)alloc((size_t)NT * 512 * 2);
  bf16_t* ha   = (bf16_t*)alloc((size_t)NA * 512 * 2);
  bf16_t* acct = (bf16_t*)alloc((size_t)NT * 512 * 2);   // ht ping-pong; qpre f32
  bf16_t* accq = (bf16_t*)alloc((size_t)NQ * 512 * 2);   // hq ping-pong; afh bf16
  bf16_t* xlb  = (bf16_t*)alloc((size_t)50000 * 512 * 2);// staging/af_emb
  bf16_t* xrb  = (bf16_t*)alloc((size_t)50000 * 512 * 2);// also rpre f32
  int* simsrc  = (int*)alloc((size_t)(E_SIM + NQ) * 4);
  int* simdst  = (int*)alloc((size_t)(E_SIM + NQ) * 4);

  // bf16-transposed weights
  bf16_t* wqp  = (bf16_t*)alloc((size_t)512 * 384 * 2);
  bf16_t* wtp  = (bf16_t*)alloc((size_t)512 * 384 * 2);
  bf16_t* wap  = (bf16_t*)alloc((size_t)512 * 384 * 2);
  bf16_t* wl   = (bf16_t*)alloc((size_t)12 * 512 * 512 * 2);
  bf16_t* wr   = (bf16_t*)alloc((size_t)12 * 512 * 512 * 2);
  bf16_t* wafp2 = (bf16_t*)alloc((size_t)512 * 64 * 2);
  bf16_t* wqh  = (bf16_t*)alloc((size_t)256 * 512 * 2);
  bf16_t* wrh0 = (bf16_t*)alloc((size_t)256 * 512 * 2);
  bf16_t* wrh1 = (bf16_t*)alloc((size_t)256 * 512 * 2);
  bf16_t* wrh2 = (bf16_t*)alloc((size_t)256 * 512 * 2);
  float* bc_t  = (float*)alloc(512 * 4);
  float* bc_q  = (float*)alloc(512 * 4);
  float* bc_a  = (float*)alloc(512 * 4);

  // CSR topology. Order: 0=gr 1=rgr 2=rlt 3=sim 4=comp 5=lt (lt LAST)
  struct Topo { const int* src; const int* dst; int Nd, E; };
  Topo topo[6] = {
    {ei_gr,        ei_gr + E_GR,     NT, E_GR},
    {ei_gr + E_GR, ei_gr,            NQ, E_GR},
    {ei_lt + E_LT, ei_lt,            NT, E_LT},
    {simsrc,       simdst,           NQ, E_SIM + NQ},
    {ei_comp,      ei_comp + E_COMP, NT, E_COMP},
    {ei_lt,        ei_lt + E_LT,     NA, E_LT},
  };
  int *deg[6], *startp[6], *eidx[6];
  for (int r = 0; r < 6; ++r) {
    deg[r]    = (int*)alloc((size_t)topo[r].Nd * 4);
    startp[r] = (int*)alloc((size_t)topo[r].Nd * 4);
    eidx[r]   = (int*)alloc((size_t)topo[r].E * 4);
  }
  int* posb = (int*)alloc((size_t)MAXE * 4);
  int* bsum = (int*)alloc(64 * 4);
  if (off > ws_size) {
    fprintf(stderr, "kernel_launch: ws too small, need %zu have %zu\n", off, ws_size);
    return;
  }

  // --- weight conversion (fp32 [K][M] -> bf16 [M][K]) ---
  convert_wT<<<dim3(512 / 32, 512 / 32, 12), 256, 0, stream>>>(conv_Wl, wl, 512, 512);
  convert_wT<<<dim3(512 / 32, 512 / 32, 12), 256, 0, stream>>>(conv_Wr, wr, 512, 512);
  convert_wT<<<dim3(512 / 32, 384 / 32, 1), 256, 0, stream>>>(qp_W, wqp, 384, 512);
  convert_wT<<<dim3(512 / 32, 384 / 32, 1), 256, 0, stream>>>(tp_W, wtp, 384, 512);
  convert_wT<<<dim3(512 / 32, 384 / 32, 1), 256, 0, stream>>>(ap_W, wap, 384, 512);
  convert_wT<<<dim3(512 / 32, 64 / 32, 1), 256, 0, stream>>>(afp_W2, wafp2, 64, 512);
  convert_wT<<<dim3(256 / 32, 512 / 32, 1), 256, 0, stream>>>(qh_W, wqh, 512, 256);
  convert_wT<<<dim3(256 / 32, 512 / 32, 1), 256, 0, stream>>>(rh_W, wrh0, 512, 256);
  convert_wT<<<dim3(256 / 32, 512 / 32, 1), 256, 0, stream>>>(rh_W + 512 * 256, wrh1, 512, 256);
  convert_wT<<<dim3(256 / 32, 512 / 32, 1), 256, 0, stream>>>(rh_W + 1024 * 256, wrh2, 512, 256);

  build_sim<<<(E_SIM + NQ + 255) / 256, 256, 0, stream>>>(ei_sim, simsrc, simdst);
  for (int r = 0; r < 6; ++r) {
    const Topo& T = topo[r];
    hipMemsetAsync(deg[r], 0, (size_t)T.Nd * 4, stream);
    csr_hist<<<(T.E + 255) / 256, 256, 0, stream>>>(T.dst, deg[r], posb, T.E);
    int nb = (T.Nd + 1023) / 1024;
    scan1<<<nb, 256, 0, stream>>>(deg[r], startp[r], bsum, T.Nd);
    scan2<<<1, 64, 0, stream>>>(bsum, nb);
    scan3<<<(T.Nd + 255) / 256, 256, 0, stream>>>(startp[r], bsum, T.Nd);
    csr_scatter<<<(T.E + 255) / 256, 256, 0, stream>>>(T.dst, startp[r], posb,
                                                       eidx[r], T.E);
  }

  // single-z launches
  auto gemm1 = [&](const bf16_t* A, const bf16_t* Bt, const float* bias, bf16_t* C,
                   int N_, int K_, int M_, const int* ridx = nullptr) {
    dim3 g(M_ / 256, (N_ + 127) / 128, 1);
    bgemm<bf16_t><<<g, 512, 0, stream>>>(A, Bt, bias, C, ridx, N_,
                                         A, Bt, bias, C, ridx, N_, K_, M_, 0);
  };
  auto gemmf1 = [&](const bf16_t* A, const bf16_t* Bt, const float* bias, float* C,
                    int N_, int K_, int M_, int acc_, const int* ridx = nullptr) {
    dim3 g(M_ / 256, (N_ + 127) / 128, 1);
    bgemm<float><<<g, 512, 0, stream>>>(A, Bt, bias, C, ridx, N_,
                                        A, Bt, bias, C, ridx, N_, K_, M_, acc_);
  };
  // z-paired launches (two independent GEMMs, same K/M/accum/CT)
  auto gemm2 = [&](const bf16_t* A0, const bf16_t* B0, const float* b0, bf16_t* C0, int N0_,
                   const bf16_t* A1, const bf16_t* B1, const float* b1, bf16_t* C1, int N1_,
                   int K_, int M_) {
    int nb0 = (N0_ + 127) / 128, nb1 = (N1_ + 127) / 128;
    dim3 g(M_ / 256, nb0 > nb1 ? nb0 : nb1, 2);
    bgemm<bf16_t><<<g, 512, 0, stream>>>(A0, B0, b0, C0, nullptr, N0_,
                                         A1, B1, b1, C1, nullptr, N1_, K_, M_, 0);
  };
  auto gemmf2 = [&](const bf16_t* A0, const bf16_t* B0, const float* b0, float* C0,
                    const int* r0, int N0_,
                    const bf16_t* A1, const bf16_t* B1, const float* b1, float* C1,
                    const int* r1, int N1_, int K_, int M_) {
    int nb0 = (N0_ + 127) / 128, nb1 = (N1_ + 127) / 128;
    dim3 g(M_ / 256, nb0 > nb1 ? nb0 : nb1, 2);
    bgemm<float><<<g, 512, 0, stream>>>(A0, B0, b0, C0, r0, N0_,
                                        A1, B1, b1, C1, r1, N1_, K_, M_, 0);
  };

  // Input projections: xq separate; xt/xa z-paired (xt->xlb, xa->xrb casts).
  f2bf_vec<<<((long)NQ * 96 + 255) / 256, 256, 0, stream>>>(xq, xlb, (long)NQ * 96);
  gemm1(xlb, wqp, qp_b, hq, NQ, 384, 512);
  f2bf_vec<<<((long)NT * 96 + 255) / 256, 256, 0, stream>>>(xt, xlb, (long)NT * 96);
  f2bf_vec<<<((long)NA * 96 + 255) / 256, 256, 0, stream>>>(xa, xrb, (long)NA * 96);
  gemm2(xlb, wtp, tp_b, ht, NT, xrb, wap, ap_b, ha, NA, 384, 512);

  // Layer loop with ping-pong h buffers; last relation per dst type carries
  // the fused mean+bias+relu (bc != null) and produces the new h in acc.
  bf16_t *hq_i = hq, *ht_i = ht, *hq_o = accq, *ht_o = acct;
  for (int l = 0; l < 2; ++l) {
    size_t b = (size_t)l * 6;
    combine_bias<<<2, 256, 0, stream>>>(conv_bias + (b + 0) * 512,
        conv_bias + (b + 3) * 512, conv_bias + (b + 5) * 512, 1.f / 3.f, bc_t);
    combine_bias<<<2, 256, 0, stream>>>(conv_bias + (b + 1) * 512,
        conv_bias + (b + 4) * 512, nullptr, 0.5f, bc_q);
    combine_bias<<<2, 256, 0, stream>>>(conv_bias + (b + 2) * 512,
        nullptr, nullptr, 1.f, bc_a);

    struct Rel { const bf16_t* xs; const bf16_t* xd; int Ns, po; bf16_t* acc;
                 int accum; const float* bc; float inv; };
    Rel rels[6] = {
      {hq_i, ht_i, NQ, 0, ht_o, 0, nullptr, 0.f},      // gr
      {ht_i, hq_i, NT, 1, hq_o, 0, nullptr, 0.f},      // rgr
      {ha,   ht_i, NA, 3, ht_o, 1, nullptr, 0.f},      // rlt
      {hq_i, hq_i, NQ, 4, hq_o, 1, bc_q, 0.5f},        // sim (final for q)
      {ht_i, ht_i, NT, 5, ht_o, 1, bc_t, 1.f / 3.f},   // comp (final for t)
      {ht_i, ha,   NT, 2, ha,   0, bc_a, 1.f},         // lt (final for a, in-place)
    };
    for (int r = 0; r < 6; ++r) {
      const Rel& R = rels[r];
      const Topo& T = topo[r];
      size_t po = (size_t)l * 6 + R.po;
      // z-paired: xs@Wl -> xlb  and  xd@Wr -> xrb in one dispatch
      gemm2(R.xs, wl + po * 512 * 512, conv_bl + po * 512, xlb, R.Ns,
            R.xd, wr + po * 512 * 512, conv_br + po * 512, xrb, T.Nd, 512, 512);
      int gb = (T.Nd + 3) / 4;
      gat_fused<<<gb, 256, 0, stream>>>(xlb, xrb, T.src, startp[r], deg[r],
                                        eidx[r], conv_att + po * 512, R.acc,
                                        T.Nd, R.accum, R.bc, R.inv);
    }
    bf16_t* t;
    t = hq_i; hq_i = hq_o; hq_o = t;
    t = ht_i; ht_i = ht_o; ht_o = t;
  }
  // after 2 swaps: hq_i==hq, ht_i==ht; scratch acct/accq free again.

  // Head: gathers fused via ridx; qpre/rpre-first z-paired.
  float* qpre = (float*)acct;
  float* rpre = (float*)xrb;
  bf16_t* afh = accq;
  const int* gsrc = ei_gen;
  const int* gdst = ei_gen + E_GEN;

  gemmf2(hq_i, wqh, qh_b, qpre, gsrc, E_GEN,
         ht_i, wrh0, rh_b, rpre, gdst, E_GEN, 512, 256);    // q_emb | t_emb
  gemmf1(ha, wrh1, nullptr, rpre, E_GEN, 512, 256, 1, gdst); // + a_emb @ rh_W[1]
  af_hidden<<<(E_GEN * 64 + 255) / 256, 256, 0, stream>>>(af, afp_W1, afp_b1,
                                                          afh, E_GEN);
  gemm1(afh, wafp2, afp_b2, xlb, E_GEN, 64, 512);            // af_emb
  gemmf1(xlb, wrh2, nullptr, rpre, E_GEN, 512, 256, 1);      // + af_emb @ rh_W[2]
  head_final<<<(E_GEN + 3) / 4, 256, 0, stream>>>(
      qpre, rpre, qh_g, qh_beta, rh_g, rh_beta, score_b, (float*)d_out, E_GEN);
}